// Round 1
// baseline (644.574 us; speedup 1.0000x reference)
//
#include <hip/hip_runtime.h>

// Upsample 2x (zero-interleave + [1,3,3,1]^2/16 blur) == separable 2-tap blend:
//   out[2i]   = 0.25*x[i-1] + 0.75*x[i]
//   out[2i+1] = 0.75*x[i]   + 0.25*x[i+1]     (zero padding at edges)
// per dimension. Input (16,128,128,128) fp32 -> output (16,128,256,256) fp32.

#define H  128
#define W  128
#define OH 256
#define OW 256

__global__ __launch_bounds__(256) void upsample2x_kernel(
    const float* __restrict__ x, float* __restrict__ out)
{
    const int tx = threadIdx.x;                 // 0..63  -> 4 output cols each
    const int ty = threadIdx.y;                 // 0..3   -> input row within block
    const int iy = (blockIdx.x << 2) + ty;      // input row 0..127
    const int p  = blockIdx.y;                  // plane (n*c), 0..2047

    const float* __restrict__ in = x + (size_t)p * (H * W);
    float*       __restrict__ o  = out + (size_t)p * (size_t)(OH * OW);

    const int K = tx << 1;                      // input col base (even)

    // Column-boundary handling: clamp address, zero the weight.
    const int   cl = (K == 0)     ? 0       : (K - 1);
    const float wl = (K == 0)     ? 0.0f    : 1.0f;
    const int   cr = (K == W - 2) ? (W - 1) : (K + 2);
    const float wr = (K == W - 2) ? 0.0f    : 1.0f;

    // h[r][j]: column-interpolated values for input rows iy-1, iy, iy+1.
    float h[3][4];
    #pragma unroll
    for (int r = 0; r < 3; ++r) {
        int ry  = iy - 1 + r;
        int ryc = ry < 0 ? 0 : (ry > H - 1 ? H - 1 : ry);
        const float* row = in + ryc * W;
        float2 m  = *(const float2*)(row + K);  // cols K, K+1 (aligned 8B)
        float a0  = row[cl] * wl;               // col K-1 (or 0)
        float a1  = m.x;
        float a2  = m.y;
        float a3  = row[cr] * wr;               // col K+2 (or 0)
        h[r][0] = 0.25f * a0 + 0.75f * a1;
        h[r][1] = 0.75f * a1 + 0.25f * a2;
        h[r][2] = 0.25f * a1 + 0.75f * a2;
        h[r][3] = 0.75f * a2 + 0.25f * a3;
    }

    // Row-boundary handling: zero the 0.25 weight of the out-of-range row.
    const float w0 = (iy > 0)     ? 0.25f : 0.0f;   // row iy-1 weight (even out row)
    const float w2 = (iy < H - 1) ? 0.25f : 0.0f;   // row iy+1 weight (odd out row)

    float4 ev, ov;
    ev.x = w0 * h[0][0] + 0.75f * h[1][0];
    ev.y = w0 * h[0][1] + 0.75f * h[1][1];
    ev.z = w0 * h[0][2] + 0.75f * h[1][2];
    ev.w = w0 * h[0][3] + 0.75f * h[1][3];
    ov.x = 0.75f * h[1][0] + w2 * h[2][0];
    ov.y = 0.75f * h[1][1] + w2 * h[2][1];
    ov.z = 0.75f * h[1][2] + w2 * h[2][2];
    ov.w = 0.75f * h[1][3] + w2 * h[2][3];

    float* orow = o + (size_t)(2 * iy) * OW + (tx << 2);
    *(float4*)(orow)      = ev;   // output row 2*iy,   cols 4tx..4tx+3
    *(float4*)(orow + OW) = ov;   // output row 2*iy+1, same cols
}

extern "C" void kernel_launch(void* const* d_in, const int* in_sizes, int n_in,
                              void* d_out, int out_size, void* d_ws, size_t ws_size,
                              hipStream_t stream)
{
    const float* x = (const float*)d_in[0];
    // d_in[1] is the 4x4 kernel; its values are fixed by construction
    // ([1,3,3,1] outer product / 16) and baked into the constants above.
    float* out = (float*)d_out;

    dim3 block(64, 4, 1);        // one wave per output row-pair; 256 thr/blk
    dim3 grid(H / 4, 16 * 128);  // 32 row-groups x 2048 planes
    upsample2x_kernel<<<grid, block, 0, stream>>>(x, out);
}